// Round 1
// baseline (141.593 us; speedup 1.0000x reference)
//
#include <hip/hip_runtime.h>
#include <cstdint>

#define B_ 2
#define N_ 8192
#define M_ 1024
#define C_ 1152
#define EPS_ 1e-8f
#define NT 32
#define CHUNK 128

// ---------------- K1: transpose feats [B][C][M] -> fm [B][M][C] ----------------
__global__ __launch_bounds__(256) void k_transpose(const float* __restrict__ feats,
                                                   float* __restrict__ fm) {
    __shared__ float tile[64][65];
    int m0 = blockIdx.x * 64;
    int c0 = blockIdx.y * 64;
    int b  = blockIdx.z;
    int tx = threadIdx.x;   // 0..63 (fast, along m on load / along c on store)
    int ty = threadIdx.y;   // 0..3
    const float* src = feats + ((size_t)b * C_ + c0) * M_ + m0;
#pragma unroll
    for (int j = 0; j < 16; ++j) {
        int cl = ty + 4 * j;
        tile[cl][tx] = src[(size_t)cl * M_ + tx];
    }
    __syncthreads();
    float* dst = fm + ((size_t)b * M_ + m0) * C_ + c0;
#pragma unroll
    for (int j = 0; j < 16; ++j) {
        int ml = ty + 4 * j;
        dst[(size_t)ml * C_ + tx] = tile[tx][ml];
    }
}

// ---------------- K2: three_nn (exact ref arithmetic emulation) ----------------
__device__ __forceinline__ bool nn_better(float d, int i, float dr, int ir) {
    // stable top_k: lower index wins ties
    return (d < dr) || ((d == dr) && (i < ir));
}
__device__ __forceinline__ void nn_insert(float d, int i,
        float& d0, int& i0, float& d1, int& i1, float& d2, int& i2) {
    if (nn_better(d, i, d2, i2)) {
        if (nn_better(d, i, d1, i1)) {
            d2 = d1; i2 = i1;
            if (nn_better(d, i, d0, i0)) { d1 = d0; i1 = i0; d0 = d; i0 = i; }
            else                         { d1 = d;  i1 = i; }
        } else { d2 = d; i2 = i; }
    }
}

__global__ __launch_bounds__(256) void k_threenn(const float* __restrict__ xyz,
                                                 const float* __restrict__ center,
                                                 int* __restrict__ idx_ws,
                                                 float* __restrict__ w_ws) {
    __shared__ float scx[M_], scy[M_], scz[M_], scc[M_];
    int b  = blockIdx.y;
    int n0 = blockIdx.x * 64;
    int t  = threadIdx.x;
    for (int i = t; i < M_; i += 256) {
        float cx = center[((size_t)b * M_ + i) * 3 + 0];
        float cy = center[((size_t)b * M_ + i) * 3 + 1];
        float cz = center[((size_t)b * M_ + i) * 3 + 2];
        scx[i] = cx; scy[i] = cy; scz[i] = cz;
        // ref: sum(center*center, -1): rounded squares, left-assoc sum, no fma
        scc[i] = __fadd_rn(__fadd_rn(__fmul_rn(cx, cx), __fmul_rn(cy, cy)),
                           __fmul_rn(cz, cz));
    }
    __syncthreads();

    int p     = t >> 2;     // 0..63: point within block
    int chunk = t & 3;      // 0..3 : center chunk
    int n     = n0 + p;
    float x = xyz[((size_t)b * N_ + n) * 3 + 0];
    float y = xyz[((size_t)b * N_ + n) * 3 + 1];
    float z = xyz[((size_t)b * N_ + n) * 3 + 2];
    float xx = __fadd_rn(__fadd_rn(__fmul_rn(x, x), __fmul_rn(y, y)),
                         __fmul_rn(z, z));

    float d0 = __builtin_inff(), d1 = __builtin_inff(), d2 = __builtin_inff();
    int   i0 = 0x7fffffff,  i1 = 0x7fffffff,  i2 = 0x7fffffff;
    int mbase = chunk * 256;
#pragma unroll 4
    for (int it = 0; it < 256; ++it) {
        int m = mbase + it;
        // ref einsum: fma-accumulated dot;  d2 = (xx+cc) - 2*dot
        float dot = __fmaf_rn(z, scz[m], __fmaf_rn(y, scy[m], __fmul_rn(x, scx[m])));
        float d   = __fsub_rn(__fadd_rn(xx, scc[m]), __fmul_rn(2.0f, dot));
        nn_insert(d, m, d0, i0, d1, i1, d2, i2);
    }
    // merge the 4 chunk-partials (lanes p*4 .. p*4+3 are in the same wave)
#pragma unroll
    for (int off = 1; off <= 2; off <<= 1) {
        float e0 = __shfl_xor(d0, off); int j0 = __shfl_xor(i0, off);
        float e1 = __shfl_xor(d1, off); int j1 = __shfl_xor(i1, off);
        float e2 = __shfl_xor(d2, off); int j2 = __shfl_xor(i2, off);
        nn_insert(e0, j0, d0, i0, d1, i1, d2, i2);
        nn_insert(e1, j1, d0, i0, d1, i1, d2, i2);
        nn_insert(e2, j2, d0, i0, d1, i1, d2, i2);
    }
    if (chunk == 0) {
        float r0 = 1.0f / __fadd_rn(d0, EPS_);
        float r1 = 1.0f / __fadd_rn(d1, EPS_);
        float r2 = 1.0f / __fadd_rn(d2, EPS_);
        float s  = __fadd_rn(__fadd_rn(r0, r1), r2);
        size_t base = ((size_t)b * N_ + n) * 3;
        idx_ws[base + 0] = i0; idx_ws[base + 1] = i1; idx_ws[base + 2] = i2;
        w_ws[base + 0] = r0 / s; w_ws[base + 1] = r1 / s; w_ws[base + 2] = r2 / s;
    }
}

// ---------------- K3: gather + weighted sum, LDS transpose for coalesced writes ----
__global__ __launch_bounds__(256) void k_interp(const float* __restrict__ fm,
                                                const int* __restrict__ idx_ws,
                                                const float* __restrict__ w_ws,
                                                float* __restrict__ out) {
    __shared__ float T[NT][CHUNK + 1];   // [point][channel], stride 129 (odd -> conflict-free col reads)
    __shared__ int   sbase[NT][3];
    __shared__ float sw[NT][3];
    int b  = blockIdx.y;
    int n0 = blockIdx.x * NT;
    int t  = threadIdx.x;
    if (t < NT) {
        size_t ib = ((size_t)b * N_ + n0 + t) * 3;
#pragma unroll
        for (int k = 0; k < 3; ++k) {
            sbase[t][k] = (b * M_ + idx_ws[ib + k]) * C_;
            sw[t][k]    = w_ws[ib + k];
        }
    }
    __syncthreads();
    int wave = t >> 6;   // 0..3
    int lane = t & 63;
    for (int c0 = 0; c0 < C_; c0 += CHUNK) {
        // compute: each wave handles 8 points; lanes span 128 channels via float2
#pragma unroll
        for (int pp = 0; pp < 8; ++pp) {
            int p = wave * 8 + pp;
            float w0 = sw[p][0], w1 = sw[p][1], w2 = sw[p][2];
            const float2 a0 = *(const float2*)(fm + sbase[p][0] + c0 + 2 * lane);
            const float2 a1 = *(const float2*)(fm + sbase[p][1] + c0 + 2 * lane);
            const float2 a2 = *(const float2*)(fm + sbase[p][2] + c0 + 2 * lane);
            float sx = __fmaf_rn(a2.x, w2, __fmaf_rn(a1.x, w1, __fmul_rn(a0.x, w0)));
            float sy = __fmaf_rn(a2.y, w2, __fmaf_rn(a1.y, w1, __fmul_rn(a0.y, w0)));
            T[p][2 * lane]     = sx;
            T[p][2 * lane + 1] = sy;
        }
        __syncthreads();
        // write out coalesced along n: lane group of 32 covers one channel row
        int p   = t & 31;
        int ccb = t >> 5;   // 0..7
#pragma unroll
        for (int i = 0; i < 16; ++i) {
            int cc = i * 8 + ccb;
            out[((size_t)b * C_ + c0 + cc) * N_ + n0 + p] = T[p][cc];
        }
        __syncthreads();
    }
}

// ---------------- launch ----------------
extern "C" void kernel_launch(void* const* d_in, const int* in_sizes, int n_in,
                              void* d_out, int out_size, void* d_ws, size_t ws_size,
                              hipStream_t stream) {
    const float* xyz    = (const float*)d_in[0];   // [B,N,3]
    const float* center = (const float*)d_in[1];   // [B,M,3]
    const float* feats  = (const float*)d_in[2];   // [B,C,M]
    float* out = (float*)d_out;                    // [B,C,N]

    // ws layout: fm [B*M*C f32] | idx [B*N*3 i32] | w [B*N*3 f32]  (~9.83 MB)
    char*  ws     = (char*)d_ws;
    float* fm     = (float*)ws;
    int*   idx_ws = (int*)(ws + (size_t)B_ * M_ * C_ * 4);
    float* w_ws   = (float*)(ws + (size_t)B_ * M_ * C_ * 4 + (size_t)B_ * N_ * 3 * 4);

    k_transpose<<<dim3(M_ / 64, C_ / 64, B_), dim3(64, 4), 0, stream>>>(feats, fm);
    k_threenn <<<dim3(N_ / 64, B_), 256, 0, stream>>>(xyz, center, idx_ws, w_ws);
    k_interp  <<<dim3(N_ / NT, B_), 256, 0, stream>>>(fm, idx_ws, w_ws, out);
}

// Round 2
// 133.228 us; speedup vs baseline: 1.0628x; 1.0628x over previous
//
#include <hip/hip_runtime.h>
#include <cstdint>

#define B_ 2
#define N_ 8192
#define M_ 1024
#define C_ 1152
#define EPS_ 1e-8f
#define NT 32
#define CHUNK 128

// ---------------- K1: transpose feats [B][C][M] -> fm [B][M][C] ----------------
__global__ __launch_bounds__(256) void k_transpose(const float* __restrict__ feats,
                                                   float* __restrict__ fm) {
    __shared__ float tile[64][65];
    int m0 = blockIdx.x * 64;
    int c0 = blockIdx.y * 64;
    int b  = blockIdx.z;
    int tx = threadIdx.x;   // 0..63
    int ty = threadIdx.y;   // 0..3
    const float* src = feats + ((size_t)b * C_ + c0) * M_ + m0;
#pragma unroll
    for (int j = 0; j < 16; ++j) {
        int cl = ty + 4 * j;
        tile[cl][tx] = src[(size_t)cl * M_ + tx];
    }
    __syncthreads();
    float* dst = fm + ((size_t)b * M_ + m0) * C_ + c0;
#pragma unroll
    for (int j = 0; j < 16; ++j) {
        int ml = ty + 4 * j;
        dst[(size_t)ml * C_ + tx] = tile[tx][ml];
    }
}

// ---------------- K2: three_nn v2 ----------------
// 16 points/block x 16 chunks/point; centers staged as float4{x,y,z,|c|^2};
// interleaved chunk access (m = c + it*16) -> 2-way-aliased (free) ds_read_b128.
__device__ __forceinline__ bool nn_better(float d, int i, float dr, int ir) {
    return (d < dr) || ((d == dr) && (i < ir));   // stable top_k tie-break
}
__device__ __forceinline__ void nn_insert(float d, int i,
        float& d0, int& i0, float& d1, int& i1, float& d2, int& i2) {
    if (nn_better(d, i, d2, i2)) {
        if (nn_better(d, i, d1, i1)) {
            d2 = d1; i2 = i1;
            if (nn_better(d, i, d0, i0)) { d1 = d0; i1 = i0; d0 = d; i0 = i; }
            else                         { d1 = d;  i1 = i; }
        } else { d2 = d; i2 = i; }
    }
}

#define NC 16   // chunks per point
#define PTS 16  // points per block

__global__ __launch_bounds__(256) void k_threenn(const float* __restrict__ xyz,
                                                 const float* __restrict__ center,
                                                 int* __restrict__ idx_ws,
                                                 float* __restrict__ w_ws) {
    __shared__ float4 sc[M_];   // 16 KB
    int b  = blockIdx.y;
    int n0 = blockIdx.x * PTS;
    int t  = threadIdx.x;
    for (int i = t; i < M_; i += 256) {
        float cx = center[((size_t)b * M_ + i) * 3 + 0];
        float cy = center[((size_t)b * M_ + i) * 3 + 1];
        float cz = center[((size_t)b * M_ + i) * 3 + 2];
        // ref: sum(center*center,-1): rounded squares, left-assoc, no fma
        float cc = __fadd_rn(__fadd_rn(__fmul_rn(cx, cx), __fmul_rn(cy, cy)),
                             __fmul_rn(cz, cz));
        sc[i] = make_float4(cx, cy, cz, cc);
    }
    __syncthreads();

    int p = t >> 4;     // 0..15: point within block
    int c = t & 15;     // 0..15: chunk
    int n = n0 + p;
    float x = xyz[((size_t)b * N_ + n) * 3 + 0];
    float y = xyz[((size_t)b * N_ + n) * 3 + 1];
    float z = xyz[((size_t)b * N_ + n) * 3 + 2];
    float xx = __fadd_rn(__fadd_rn(__fmul_rn(x, x), __fmul_rn(y, y)),
                         __fmul_rn(z, z));

    float d0 = __builtin_inff(), d1 = __builtin_inff(), d2 = __builtin_inff();
    int   i0 = 0x7fffffff,  i1 = 0x7fffffff,  i2 = 0x7fffffff;
#pragma unroll 4
    for (int it = 0; it < M_ / NC; ++it) {
        int m = c + it * NC;                    // interleaved: 16 consecutive float4s/wave-group
        float4 v = sc[m];
        // ref einsum: fma-accumulated dot;  d = (xx+cc) - 2*dot
        float dot = __fmaf_rn(z, v.z, __fmaf_rn(y, v.y, __fmul_rn(x, v.x)));
        float d   = __fsub_rn(__fadd_rn(xx, v.w), __fmul_rn(2.0f, dot));
        nn_insert(d, m, d0, i0, d1, i1, d2, i2);
    }
    // merge 16 chunk-partials (lanes p*16 .. p*16+15 are in the same wave)
#pragma unroll
    for (int off = 1; off <= 8; off <<= 1) {
        float e0 = __shfl_xor(d0, off); int j0 = __shfl_xor(i0, off);
        float e1 = __shfl_xor(d1, off); int j1 = __shfl_xor(i1, off);
        float e2 = __shfl_xor(d2, off); int j2 = __shfl_xor(i2, off);
        nn_insert(e0, j0, d0, i0, d1, i1, d2, i2);
        nn_insert(e1, j1, d0, i0, d1, i1, d2, i2);
        nn_insert(e2, j2, d0, i0, d1, i1, d2, i2);
    }
    if (c == 0) {
        float r0 = 1.0f / __fadd_rn(d0, EPS_);
        float r1 = 1.0f / __fadd_rn(d1, EPS_);
        float r2 = 1.0f / __fadd_rn(d2, EPS_);
        float s  = __fadd_rn(__fadd_rn(r0, r1), r2);
        size_t base = ((size_t)b * N_ + n) * 3;
        idx_ws[base + 0] = i0; idx_ws[base + 1] = i1; idx_ws[base + 2] = i2;
        w_ws[base + 0] = r0 / s; w_ws[base + 1] = r1 / s; w_ws[base + 2] = r2 / s;
    }
}

// ---------------- K3: gather + weighted sum, LDS transpose for coalesced writes ----
__global__ __launch_bounds__(256) void k_interp(const float* __restrict__ fm,
                                                const int* __restrict__ idx_ws,
                                                const float* __restrict__ w_ws,
                                                float* __restrict__ out) {
    __shared__ float T[NT][CHUNK + 1];
    __shared__ int   sbase[NT][3];
    __shared__ float sw[NT][3];
    int b  = blockIdx.y;
    int n0 = blockIdx.x * NT;
    int t  = threadIdx.x;
    if (t < NT) {
        size_t ib = ((size_t)b * N_ + n0 + t) * 3;
#pragma unroll
        for (int k = 0; k < 3; ++k) {
            sbase[t][k] = (b * M_ + idx_ws[ib + k]) * C_;
            sw[t][k]    = w_ws[ib + k];
        }
    }
    __syncthreads();
    int wave = t >> 6;
    int lane = t & 63;
    for (int c0 = 0; c0 < C_; c0 += CHUNK) {
#pragma unroll
        for (int pp = 0; pp < 8; ++pp) {
            int p = wave * 8 + pp;
            float w0 = sw[p][0], w1 = sw[p][1], w2 = sw[p][2];
            const float2 a0 = *(const float2*)(fm + sbase[p][0] + c0 + 2 * lane);
            const float2 a1 = *(const float2*)(fm + sbase[p][1] + c0 + 2 * lane);
            const float2 a2 = *(const float2*)(fm + sbase[p][2] + c0 + 2 * lane);
            float sx = __fmaf_rn(a2.x, w2, __fmaf_rn(a1.x, w1, __fmul_rn(a0.x, w0)));
            float sy = __fmaf_rn(a2.y, w2, __fmaf_rn(a1.y, w1, __fmul_rn(a0.y, w0)));
            T[p][2 * lane]     = sx;
            T[p][2 * lane + 1] = sy;
        }
        __syncthreads();
        int p   = t & 31;
        int ccb = t >> 5;
#pragma unroll
        for (int i = 0; i < 16; ++i) {
            int cc = i * 8 + ccb;
            out[((size_t)b * C_ + c0 + cc) * N_ + n0 + p] = T[p][cc];
        }
        __syncthreads();
    }
}

// ---------------- launch ----------------
extern "C" void kernel_launch(void* const* d_in, const int* in_sizes, int n_in,
                              void* d_out, int out_size, void* d_ws, size_t ws_size,
                              hipStream_t stream) {
    const float* xyz    = (const float*)d_in[0];   // [B,N,3]
    const float* center = (const float*)d_in[1];   // [B,M,3]
    const float* feats  = (const float*)d_in[2];   // [B,C,M]
    float* out = (float*)d_out;                    // [B,C,N]

    char*  ws     = (char*)d_ws;
    float* fm     = (float*)ws;
    int*   idx_ws = (int*)(ws + (size_t)B_ * M_ * C_ * 4);
    float* w_ws   = (float*)(ws + (size_t)B_ * M_ * C_ * 4 + (size_t)B_ * N_ * 3 * 4);

    k_transpose<<<dim3(M_ / 64, C_ / 64, B_), dim3(64, 4), 0, stream>>>(feats, fm);
    k_threenn <<<dim3(N_ / PTS, B_), 256, 0, stream>>>(xyz, center, idx_ws, w_ws);
    k_interp  <<<dim3(N_ / NT, B_), 256, 0, stream>>>(fm, idx_ws, w_ws, out);
}

// Round 3
// 65.372 us; speedup vs baseline: 2.1660x; 2.0380x over previous
//
#include <hip/hip_runtime.h>
#include <cstdint>

#define B_ 2
#define N_ 8192
#define M_ 1024
#define C_ 1152
#define EPS_ 1e-8f
#define NT 32
#define CHUNK 128

// ---------------- K1: transpose feats [B][C][M] -> fm [B][M][C] ----------------
__global__ __launch_bounds__(256) void k_transpose(const float* __restrict__ feats,
                                                   float* __restrict__ fm) {
    __shared__ float tile[64][65];
    int m0 = blockIdx.x * 64;
    int c0 = blockIdx.y * 64;
    int b  = blockIdx.z;
    int tx = threadIdx.x;   // 0..63
    int ty = threadIdx.y;   // 0..3
    const float* src = feats + ((size_t)b * C_ + c0) * M_ + m0;
#pragma unroll
    for (int j = 0; j < 16; ++j) {
        int cl = ty + 4 * j;
        tile[cl][tx] = src[(size_t)cl * M_ + tx];
    }
    __syncthreads();
    float* dst = fm + ((size_t)b * M_ + m0) * C_ + c0;
#pragma unroll
    for (int j = 0; j < 16; ++j) {
        int ml = ty + 4 * j;
        dst[(size_t)ml * C_ + tx] = tile[tx][ml];
    }
}

// ---------------- K2: three_nn v3 — branchless packed-u64 top-3 ----------------
// key = (order_preserving_bits(d) << 32) | m :
//   u64 compare == lexicographic (smaller d first, then smaller index) ==
//   jax.lax.top_k's stable tie-break. Insert = 3 compare-swap cascade, zero branches.

__device__ __forceinline__ unsigned long long pack_di(float d, int m) {
    unsigned u = __float_as_uint(d);
    unsigned s = (unsigned)((int)u >> 31);          // 0 or 0xFFFFFFFF
    u ^= (s | 0x80000000u);                          // monotone order-preserving map
    return ((unsigned long long)u << 32) | (unsigned)m;
}
__device__ __forceinline__ float unpack_d(unsigned long long k) {
    unsigned u = (unsigned)(k >> 32);
    unsigned s = (unsigned)((int)u >> 31);
    u ^= (~s | 0x80000000u);                         // inverse map
    return __uint_as_float(u);
}
__device__ __forceinline__ void kinsert(unsigned long long p,
        unsigned long long& k0, unsigned long long& k1, unsigned long long& k2) {
    unsigned long long t;
    bool c0 = p < k0; t = c0 ? k0 : p; k0 = c0 ? p : k0; p = t;
    bool c1 = p < k1; t = c1 ? k1 : p; k1 = c1 ? p : k1; p = t;
    k2 = (p < k2) ? p : k2;
}
__device__ __forceinline__ unsigned long long shfl_xor_u64(unsigned long long v, int off) {
    int lo = __shfl_xor((int)(unsigned)v, off);
    int hi = __shfl_xor((int)(unsigned)(v >> 32), off);
    return ((unsigned long long)(unsigned)hi << 32) | (unsigned)lo;
}

#define NC 16   // chunks per point
#define PTS 16  // points per block

__global__ __launch_bounds__(256) void k_threenn(const float* __restrict__ xyz,
                                                 const float* __restrict__ center,
                                                 int* __restrict__ idx_ws,
                                                 float* __restrict__ w_ws) {
    __shared__ float4 sc[M_];   // 16 KB
    int b  = blockIdx.y;
    int n0 = blockIdx.x * PTS;
    int t  = threadIdx.x;
    for (int i = t; i < M_; i += 256) {
        float cx = center[((size_t)b * M_ + i) * 3 + 0];
        float cy = center[((size_t)b * M_ + i) * 3 + 1];
        float cz = center[((size_t)b * M_ + i) * 3 + 2];
        // ref: sum(center*center,-1): rounded squares, left-assoc, no fma
        float cc = __fadd_rn(__fadd_rn(__fmul_rn(cx, cx), __fmul_rn(cy, cy)),
                             __fmul_rn(cz, cz));
        sc[i] = make_float4(cx, cy, cz, cc);
    }
    __syncthreads();

    int p = t >> 4;     // 0..15: point within block
    int c = t & 15;     // 0..15: chunk
    int n = n0 + p;
    float x = xyz[((size_t)b * N_ + n) * 3 + 0];
    float y = xyz[((size_t)b * N_ + n) * 3 + 1];
    float z = xyz[((size_t)b * N_ + n) * 3 + 2];
    float xx = __fadd_rn(__fadd_rn(__fmul_rn(x, x), __fmul_rn(y, y)),
                         __fmul_rn(z, z));

    unsigned long long k0 = ~0ull, k1 = ~0ull, k2 = ~0ull;
#pragma unroll 4
    for (int it = 0; it < M_ / NC; ++it) {
        int m = c + it * NC;                    // interleaved: 2-way-aliased b128 (free)
        float4 v = sc[m];
        // ref einsum: fma-accumulated dot;  d = (xx+cc) - 2*dot  (bit-exact vs R2)
        float dot = __fmaf_rn(z, v.z, __fmaf_rn(y, v.y, __fmul_rn(x, v.x)));
        float d   = __fsub_rn(__fadd_rn(xx, v.w), __fmul_rn(2.0f, dot));
        kinsert(pack_di(d, m), k0, k1, k2);
    }
    // merge 16 chunk-partials (lanes p*16 .. p*16+15 are in the same wave)
#pragma unroll
    for (int off = 1; off <= 8; off <<= 1) {
        unsigned long long e0 = shfl_xor_u64(k0, off);
        unsigned long long e1 = shfl_xor_u64(k1, off);
        unsigned long long e2 = shfl_xor_u64(k2, off);
        kinsert(e0, k0, k1, k2);
        kinsert(e1, k0, k1, k2);
        kinsert(e2, k0, k1, k2);
    }
    if (c == 0) {
        float r0 = 1.0f / __fadd_rn(unpack_d(k0), EPS_);
        float r1 = 1.0f / __fadd_rn(unpack_d(k1), EPS_);
        float r2 = 1.0f / __fadd_rn(unpack_d(k2), EPS_);
        float s  = __fadd_rn(__fadd_rn(r0, r1), r2);
        size_t base = ((size_t)b * N_ + n) * 3;
        idx_ws[base + 0] = (int)(unsigned)k0;
        idx_ws[base + 1] = (int)(unsigned)k1;
        idx_ws[base + 2] = (int)(unsigned)k2;
        w_ws[base + 0] = r0 / s; w_ws[base + 1] = r1 / s; w_ws[base + 2] = r2 / s;
    }
}

// ---------------- K3: gather + weighted sum, LDS transpose for coalesced writes ----
__global__ __launch_bounds__(256) void k_interp(const float* __restrict__ fm,
                                                const int* __restrict__ idx_ws,
                                                const float* __restrict__ w_ws,
                                                float* __restrict__ out) {
    __shared__ float T[NT][CHUNK + 1];
    __shared__ int   sbase[NT][3];
    __shared__ float sw[NT][3];
    int b  = blockIdx.y;
    int n0 = blockIdx.x * NT;
    int t  = threadIdx.x;
    if (t < NT) {
        size_t ib = ((size_t)b * N_ + n0 + t) * 3;
#pragma unroll
        for (int k = 0; k < 3; ++k) {
            sbase[t][k] = (b * M_ + idx_ws[ib + k]) * C_;
            sw[t][k]    = w_ws[ib + k];
        }
    }
    __syncthreads();
    int wave = t >> 6;
    int lane = t & 63;
    for (int c0 = 0; c0 < C_; c0 += CHUNK) {
#pragma unroll
        for (int pp = 0; pp < 8; ++pp) {
            int p = wave * 8 + pp;
            float w0 = sw[p][0], w1 = sw[p][1], w2 = sw[p][2];
            const float2 a0 = *(const float2*)(fm + sbase[p][0] + c0 + 2 * lane);
            const float2 a1 = *(const float2*)(fm + sbase[p][1] + c0 + 2 * lane);
            const float2 a2 = *(const float2*)(fm + sbase[p][2] + c0 + 2 * lane);
            float sx = __fmaf_rn(a2.x, w2, __fmaf_rn(a1.x, w1, __fmul_rn(a0.x, w0)));
            float sy = __fmaf_rn(a2.y, w2, __fmaf_rn(a1.y, w1, __fmul_rn(a0.y, w0)));
            T[p][2 * lane]     = sx;
            T[p][2 * lane + 1] = sy;
        }
        __syncthreads();
        int p   = t & 31;
        int ccb = t >> 5;
#pragma unroll
        for (int i = 0; i < 16; ++i) {
            int cc = i * 8 + ccb;
            out[((size_t)b * C_ + c0 + cc) * N_ + n0 + p] = T[p][cc];
        }
        __syncthreads();
    }
}

// ---------------- launch ----------------
extern "C" void kernel_launch(void* const* d_in, const int* in_sizes, int n_in,
                              void* d_out, int out_size, void* d_ws, size_t ws_size,
                              hipStream_t stream) {
    const float* xyz    = (const float*)d_in[0];   // [B,N,3]
    const float* center = (const float*)d_in[1];   // [B,M,3]
    const float* feats  = (const float*)d_in[2];   // [B,C,M]
    float* out = (float*)d_out;                    // [B,C,N]

    char*  ws     = (char*)d_ws;
    float* fm     = (float*)ws;
    int*   idx_ws = (int*)(ws + (size_t)B_ * M_ * C_ * 4);
    float* w_ws   = (float*)(ws + (size_t)B_ * M_ * C_ * 4 + (size_t)B_ * N_ * 3 * 4);

    k_transpose<<<dim3(M_ / 64, C_ / 64, B_), dim3(64, 4), 0, stream>>>(feats, fm);
    k_threenn <<<dim3(N_ / PTS, B_), 256, 0, stream>>>(xyz, center, idx_ws, w_ws);
    k_interp  <<<dim3(N_ / NT, B_), 256, 0, stream>>>(fm, idx_ws, w_ws, out);
}

// Round 4
// 44.897 us; speedup vs baseline: 3.1538x; 1.4561x over previous
//
#include <hip/hip_runtime.h>
#include <cstdint>

#define B_ 2
#define N_ 8192
#define M_ 1024
#define C_ 1152
#define EPS_ 1e-8f
#define NT 32
#define CHUNK 128

// bf16 helpers (RNE, matches __float2bfloat16 default rounding)
__device__ __forceinline__ unsigned short f2bf(float f) {
    unsigned u = __float_as_uint(f);
    u += 0x7fffu + ((u >> 16) & 1u);
    return (unsigned short)(u >> 16);
}
__device__ __forceinline__ float bf2f(unsigned short h) {
    return __uint_as_float(((unsigned)h) << 16);
}

// ---------------- K1: transpose feats [B][C][M] f32 -> fm [B][M][C] bf16 ----------------
__global__ __launch_bounds__(256) void k_transpose(const float* __restrict__ feats,
                                                   unsigned short* __restrict__ fm) {
    __shared__ float tile[64][65];
    int m0 = blockIdx.x * 64;
    int c0 = blockIdx.y * 64;
    int b  = blockIdx.z;
    int tx = threadIdx.x;   // 0..63
    int ty = threadIdx.y;   // 0..3
    const float* src = feats + ((size_t)b * C_ + c0) * M_ + m0;
#pragma unroll
    for (int j = 0; j < 16; ++j) {
        int cl = ty + 4 * j;
        tile[cl][tx] = __builtin_nontemporal_load(&src[(size_t)cl * M_ + tx]);
    }
    __syncthreads();
    unsigned short* dst = fm + ((size_t)b * M_ + m0) * C_ + c0;
#pragma unroll
    for (int j = 0; j < 16; ++j) {
        int ml = ty + 4 * j;
        dst[(size_t)ml * C_ + tx] = f2bf(tile[tx][ml]);  // keep cached: interp re-reads fm
    }
}

// ---------------- K2: three_nn — branchless packed-u64 top-3 (unchanged from R3) ----------------
__device__ __forceinline__ unsigned long long pack_di(float d, int m) {
    unsigned u = __float_as_uint(d);
    unsigned s = (unsigned)((int)u >> 31);
    u ^= (s | 0x80000000u);
    return ((unsigned long long)u << 32) | (unsigned)m;
}
__device__ __forceinline__ float unpack_d(unsigned long long k) {
    unsigned u = (unsigned)(k >> 32);
    unsigned s = (unsigned)((int)u >> 31);
    u ^= (~s | 0x80000000u);
    return __uint_as_float(u);
}
__device__ __forceinline__ void kinsert(unsigned long long p,
        unsigned long long& k0, unsigned long long& k1, unsigned long long& k2) {
    unsigned long long t;
    bool c0 = p < k0; t = c0 ? k0 : p; k0 = c0 ? p : k0; p = t;
    bool c1 = p < k1; t = c1 ? k1 : p; k1 = c1 ? p : k1; p = t;
    k2 = (p < k2) ? p : k2;
}
__device__ __forceinline__ unsigned long long shfl_xor_u64(unsigned long long v, int off) {
    int lo = __shfl_xor((int)(unsigned)v, off);
    int hi = __shfl_xor((int)(unsigned)(v >> 32), off);
    return ((unsigned long long)(unsigned)hi << 32) | (unsigned)lo;
}

#define NC 16   // chunks per point
#define PTS 16  // points per block

__global__ __launch_bounds__(256) void k_threenn(const float* __restrict__ xyz,
                                                 const float* __restrict__ center,
                                                 int* __restrict__ idx_ws,
                                                 float* __restrict__ w_ws) {
    __shared__ float4 sc[M_];   // 16 KB
    int b  = blockIdx.y;
    int n0 = blockIdx.x * PTS;
    int t  = threadIdx.x;
    for (int i = t; i < M_; i += 256) {
        float cx = center[((size_t)b * M_ + i) * 3 + 0];
        float cy = center[((size_t)b * M_ + i) * 3 + 1];
        float cz = center[((size_t)b * M_ + i) * 3 + 2];
        // ref: sum(center*center,-1): rounded squares, left-assoc, no fma
        float cc = __fadd_rn(__fadd_rn(__fmul_rn(cx, cx), __fmul_rn(cy, cy)),
                             __fmul_rn(cz, cz));
        sc[i] = make_float4(cx, cy, cz, cc);
    }
    __syncthreads();

    int p = t >> 4;
    int c = t & 15;
    int n = n0 + p;
    float x = xyz[((size_t)b * N_ + n) * 3 + 0];
    float y = xyz[((size_t)b * N_ + n) * 3 + 1];
    float z = xyz[((size_t)b * N_ + n) * 3 + 2];
    float xx = __fadd_rn(__fadd_rn(__fmul_rn(x, x), __fmul_rn(y, y)),
                         __fmul_rn(z, z));

    unsigned long long k0 = ~0ull, k1 = ~0ull, k2 = ~0ull;
#pragma unroll 4
    for (int it = 0; it < M_ / NC; ++it) {
        int m = c + it * NC;
        float4 v = sc[m];
        // ref einsum: fma-accumulated dot;  d = (xx+cc) - 2*dot  (bit-exact vs R2/R3)
        float dot = __fmaf_rn(z, v.z, __fmaf_rn(y, v.y, __fmul_rn(x, v.x)));
        float d   = __fsub_rn(__fadd_rn(xx, v.w), __fmul_rn(2.0f, dot));
        kinsert(pack_di(d, m), k0, k1, k2);
    }
#pragma unroll
    for (int off = 1; off <= 8; off <<= 1) {
        unsigned long long e0 = shfl_xor_u64(k0, off);
        unsigned long long e1 = shfl_xor_u64(k1, off);
        unsigned long long e2 = shfl_xor_u64(k2, off);
        kinsert(e0, k0, k1, k2);
        kinsert(e1, k0, k1, k2);
        kinsert(e2, k0, k1, k2);
    }
    if (c == 0) {
        float r0 = 1.0f / __fadd_rn(unpack_d(k0), EPS_);
        float r1 = 1.0f / __fadd_rn(unpack_d(k1), EPS_);
        float r2 = 1.0f / __fadd_rn(unpack_d(k2), EPS_);
        float s  = __fadd_rn(__fadd_rn(r0, r1), r2);
        size_t base = ((size_t)b * N_ + n) * 3;
        idx_ws[base + 0] = (int)(unsigned)k0;
        idx_ws[base + 1] = (int)(unsigned)k1;
        idx_ws[base + 2] = (int)(unsigned)k2;
        w_ws[base + 0] = r0 / s; w_ws[base + 1] = r1 / s; w_ws[base + 2] = r2 / s;
    }
}

// ---------------- K3: gather(bf16) + weighted sum; chunk is a grid dim ----------------
__global__ __launch_bounds__(256) void k_interp(const unsigned short* __restrict__ fm,
                                                const int* __restrict__ idx_ws,
                                                const float* __restrict__ w_ws,
                                                float* __restrict__ out) {
    __shared__ float T[NT][CHUNK + 1];   // [point][channel], odd stride -> conflict-free cols
    __shared__ int   sbase[NT][3];
    __shared__ float sw[NT][3];
    int b  = blockIdx.z;
    int c0 = blockIdx.y * CHUNK;
    int n0 = blockIdx.x * NT;
    int t  = threadIdx.x;
    if (t < NT) {
        size_t ib = ((size_t)b * N_ + n0 + t) * 3;
#pragma unroll
        for (int k = 0; k < 3; ++k) {
            sbase[t][k] = (b * M_ + idx_ws[ib + k]) * C_;
            sw[t][k]    = w_ws[ib + k];
        }
    }
    __syncthreads();
    int wave = t >> 6;
    int lane = t & 63;
#pragma unroll
    for (int pp = 0; pp < 8; ++pp) {
        int p = wave * 8 + pp;
        float w0 = sw[p][0], w1 = sw[p][1], w2 = sw[p][2];
        const ushort2 a0 = *(const ushort2*)(fm + sbase[p][0] + c0 + 2 * lane);
        const ushort2 a1 = *(const ushort2*)(fm + sbase[p][1] + c0 + 2 * lane);
        const ushort2 a2 = *(const ushort2*)(fm + sbase[p][2] + c0 + 2 * lane);
        float sx = __fmaf_rn(bf2f(a2.x), w2, __fmaf_rn(bf2f(a1.x), w1, __fmul_rn(bf2f(a0.x), w0)));
        float sy = __fmaf_rn(bf2f(a2.y), w2, __fmaf_rn(bf2f(a1.y), w1, __fmul_rn(bf2f(a0.y), w0)));
        T[p][2 * lane]     = sx;
        T[p][2 * lane + 1] = sy;
    }
    __syncthreads();
    // coalesced writes along n; nontemporal: out is write-once, keep L2 for fm
    int p   = t & 31;
    int ccb = t >> 5;
#pragma unroll
    for (int i = 0; i < 16; ++i) {
        int cc = i * 8 + ccb;
        __builtin_nontemporal_store(T[p][cc],
            &out[((size_t)b * C_ + c0 + cc) * N_ + n0 + p]);
    }
}

// ---------------- launch ----------------
extern "C" void kernel_launch(void* const* d_in, const int* in_sizes, int n_in,
                              void* d_out, int out_size, void* d_ws, size_t ws_size,
                              hipStream_t stream) {
    const float* xyz    = (const float*)d_in[0];   // [B,N,3]
    const float* center = (const float*)d_in[1];   // [B,M,3]
    const float* feats  = (const float*)d_in[2];   // [B,C,M]
    float* out = (float*)d_out;                    // [B,C,N]

    // ws layout: fm bf16 [B*M*C] | idx [B*N*3 i32] | w [B*N*3 f32]  (~5.0 MB)
    char*           ws     = (char*)d_ws;
    unsigned short* fm     = (unsigned short*)ws;
    int*            idx_ws = (int*)(ws + (size_t)B_ * M_ * C_ * 2);
    float*          w_ws   = (float*)(ws + (size_t)B_ * M_ * C_ * 2 + (size_t)B_ * N_ * 3 * 4);

    k_transpose<<<dim3(M_ / 64, C_ / 64, B_), dim3(64, 4), 0, stream>>>(feats, fm);
    k_threenn <<<dim3(N_ / PTS, B_), 256, 0, stream>>>(xyz, center, idx_ws, w_ws);
    k_interp  <<<dim3(N_ / NT, C_ / CHUNK, B_), 256, 0, stream>>>(fm, idx_ws, w_ws, out);
}

// Round 6
// 41.949 us; speedup vs baseline: 3.3754x; 1.0703x over previous
//
#include <hip/hip_runtime.h>
#include <cstdint>

#define B_ 2
#define N_ 8192
#define M_ 1024
#define C_ 1152
#define EPS_ 1e-8f
#define NT 32
#define CHUNK 128
#define NBN (N_ / NT)      // 256 n-blocks
#define NBC (C_ / CHUNK)   // 9 c-blocks

typedef float f32x4 __attribute__((ext_vector_type(4)));   // clang vector: OK for nontemporal builtins

// bf16 helpers (RNE)
__device__ __forceinline__ unsigned short f2bf(float f) {
    unsigned u = __float_as_uint(f);
    u += 0x7fffu + ((u >> 16) & 1u);
    return (unsigned short)(u >> 16);
}
__device__ __forceinline__ float bf2f(unsigned short h) {
    return __uint_as_float(((unsigned)h) << 16);
}

// ---------------- K1: transpose feats [B][C][M] f32 -> fm [B][M][C] bf16 ----------------
__global__ __launch_bounds__(256) void k_transpose(const float* __restrict__ feats,
                                                   unsigned short* __restrict__ fm) {
    __shared__ float tile[64][65];
    int m0 = blockIdx.x * 64;
    int c0 = blockIdx.y * 64;
    int b  = blockIdx.z;
    int tx = threadIdx.x;
    int ty = threadIdx.y;
    const float* src = feats + ((size_t)b * C_ + c0) * M_ + m0;
#pragma unroll
    for (int j = 0; j < 16; ++j) {
        int cl = ty + 4 * j;
        tile[cl][tx] = __builtin_nontemporal_load(&src[(size_t)cl * M_ + tx]);
    }
    __syncthreads();
    unsigned short* dst = fm + ((size_t)b * M_ + m0) * C_ + c0;
#pragma unroll
    for (int j = 0; j < 16; ++j) {
        int ml = ty + 4 * j;
        dst[(size_t)ml * C_ + tx] = f2bf(tile[tx][ml]);
    }
}

// ---------------- K2: three_nn — branchless packed-u64 top-3 (unchanged) ----------------
__device__ __forceinline__ unsigned long long pack_di(float d, int m) {
    unsigned u = __float_as_uint(d);
    unsigned s = (unsigned)((int)u >> 31);
    u ^= (s | 0x80000000u);
    return ((unsigned long long)u << 32) | (unsigned)m;
}
__device__ __forceinline__ float unpack_d(unsigned long long k) {
    unsigned u = (unsigned)(k >> 32);
    unsigned s = (unsigned)((int)u >> 31);
    u ^= (~s | 0x80000000u);
    return __uint_as_float(u);
}
__device__ __forceinline__ void kinsert(unsigned long long p,
        unsigned long long& k0, unsigned long long& k1, unsigned long long& k2) {
    unsigned long long t;
    bool c0 = p < k0; t = c0 ? k0 : p; k0 = c0 ? p : k0; p = t;
    bool c1 = p < k1; t = c1 ? k1 : p; k1 = c1 ? p : k1; p = t;
    k2 = (p < k2) ? p : k2;
}
__device__ __forceinline__ unsigned long long shfl_xor_u64(unsigned long long v, int off) {
    int lo = __shfl_xor((int)(unsigned)v, off);
    int hi = __shfl_xor((int)(unsigned)(v >> 32), off);
    return ((unsigned long long)(unsigned)hi << 32) | (unsigned)lo;
}

#define NC 16
#define PTS 16

__global__ __launch_bounds__(256) void k_threenn(const float* __restrict__ xyz,
                                                 const float* __restrict__ center,
                                                 int* __restrict__ idx_ws,
                                                 float* __restrict__ w_ws) {
    __shared__ float4 sc[M_];
    int b  = blockIdx.y;
    int n0 = blockIdx.x * PTS;
    int t  = threadIdx.x;
    for (int i = t; i < M_; i += 256) {
        float cx = center[((size_t)b * M_ + i) * 3 + 0];
        float cy = center[((size_t)b * M_ + i) * 3 + 1];
        float cz = center[((size_t)b * M_ + i) * 3 + 2];
        float cc = __fadd_rn(__fadd_rn(__fmul_rn(cx, cx), __fmul_rn(cy, cy)),
                             __fmul_rn(cz, cz));
        sc[i] = make_float4(cx, cy, cz, cc);
    }
    __syncthreads();

    int p = t >> 4;
    int c = t & 15;
    int n = n0 + p;
    float x = xyz[((size_t)b * N_ + n) * 3 + 0];
    float y = xyz[((size_t)b * N_ + n) * 3 + 1];
    float z = xyz[((size_t)b * N_ + n) * 3 + 2];
    float xx = __fadd_rn(__fadd_rn(__fmul_rn(x, x), __fmul_rn(y, y)),
                         __fmul_rn(z, z));

    unsigned long long k0 = ~0ull, k1 = ~0ull, k2 = ~0ull;
#pragma unroll 4
    for (int it = 0; it < M_ / NC; ++it) {
        int m = c + it * NC;
        float4 v = sc[m];
        float dot = __fmaf_rn(z, v.z, __fmaf_rn(y, v.y, __fmul_rn(x, v.x)));
        float d   = __fsub_rn(__fadd_rn(xx, v.w), __fmul_rn(2.0f, dot));
        kinsert(pack_di(d, m), k0, k1, k2);
    }
#pragma unroll
    for (int off = 1; off <= 8; off <<= 1) {
        unsigned long long e0 = shfl_xor_u64(k0, off);
        unsigned long long e1 = shfl_xor_u64(k1, off);
        unsigned long long e2 = shfl_xor_u64(k2, off);
        kinsert(e0, k0, k1, k2);
        kinsert(e1, k0, k1, k2);
        kinsert(e2, k0, k1, k2);
    }
    if (c == 0) {
        float r0 = 1.0f / __fadd_rn(unpack_d(k0), EPS_);
        float r1 = 1.0f / __fadd_rn(unpack_d(k1), EPS_);
        float r2 = 1.0f / __fadd_rn(unpack_d(k2), EPS_);
        float s  = __fadd_rn(__fadd_rn(r0, r1), r2);
        size_t base = ((size_t)b * N_ + n) * 3;
        idx_ws[base + 0] = (int)(unsigned)k0;
        idx_ws[base + 1] = (int)(unsigned)k1;
        idx_ws[base + 2] = (int)(unsigned)k2;
        w_ws[base + 0] = r0 / s; w_ws[base + 1] = r1 / s; w_ws[base + 2] = r2 / s;
    }
}

// ---------------- K3: gather(bf16,ushort4) + weighted sum; XCD-pinned 1D grid ----------------
// Grid is flat 4608 blocks. flat&7 = XCD slot (dispatch i%8 heuristic):
// slots 0-3 -> batch 0, slots 4-7 -> batch 1, so each XCD's L2 only holds
// one batch's fm table (2.36 MB < 4 MiB -> L2-resident gathers).
__global__ __launch_bounds__(256) void k_interp(const unsigned short* __restrict__ fm,
                                                const int* __restrict__ idx_ws,
                                                const float* __restrict__ w_ws,
                                                float* __restrict__ out) {
    __shared__ float T[NT][CHUNK + 1];   // stride 129
    __shared__ int   sbase[NT][3];
    __shared__ float sw[NT][3];
    int flat = blockIdx.x;
    int slot = flat & 7;
    int b    = slot >> 2;
    int idx  = (flat >> 3) * 4 + (slot & 3);   // 0..2303 per batch
    int n0   = (idx & (NBN - 1)) * NT;
    int c0   = (idx >> 8) * CHUNK;
    int t    = threadIdx.x;
    if (t < NT) {
        size_t ib = ((size_t)b * N_ + n0 + t) * 3;
#pragma unroll
        for (int k = 0; k < 3; ++k) {
            sbase[t][k] = (b * M_ + idx_ws[ib + k]) * C_;
            sw[t][k]    = w_ws[ib + k];
        }
    }
    __syncthreads();
    int wave = t >> 6;
    int lane = t & 63;
    int half = lane >> 5;          // 0/1: point selector within wave
    int cl   = (lane & 31) * 4;    // 4-channel group
#pragma unroll
    for (int pp = 0; pp < 4; ++pp) {
        int p = pp * 8 + wave * 2 + half;
        float w0 = sw[p][0], w1 = sw[p][1], w2 = sw[p][2];
        const ushort4 a0 = *(const ushort4*)(fm + sbase[p][0] + c0 + cl);
        const ushort4 a1 = *(const ushort4*)(fm + sbase[p][1] + c0 + cl);
        const ushort4 a2 = *(const ushort4*)(fm + sbase[p][2] + c0 + cl);
        T[p][cl + 0] = __fmaf_rn(bf2f(a2.x), w2, __fmaf_rn(bf2f(a1.x), w1, __fmul_rn(bf2f(a0.x), w0)));
        T[p][cl + 1] = __fmaf_rn(bf2f(a2.y), w2, __fmaf_rn(bf2f(a1.y), w1, __fmul_rn(bf2f(a0.y), w0)));
        T[p][cl + 2] = __fmaf_rn(bf2f(a2.z), w2, __fmaf_rn(bf2f(a1.z), w1, __fmul_rn(bf2f(a0.z), w0)));
        T[p][cl + 3] = __fmaf_rn(bf2f(a2.w), w2, __fmaf_rn(bf2f(a1.w), w1, __fmul_rn(bf2f(a0.w), w0)));
    }
    __syncthreads();
    // write phase: each thread assembles f32x4 along n -> wide NT stores
    int p4  = (t & 7) * 4;
    int ccb = t >> 3;              // 0..31
#pragma unroll
    for (int r = 0; r < 4; ++r) {
        int cc = r * 32 + ccb;
        f32x4 v = { T[p4 + 0][cc], T[p4 + 1][cc], T[p4 + 2][cc], T[p4 + 3][cc] };
        __builtin_nontemporal_store(v,
            (f32x4*)&out[((size_t)b * C_ + c0 + cc) * N_ + n0 + p4]);
    }
}

// ---------------- launch ----------------
extern "C" void kernel_launch(void* const* d_in, const int* in_sizes, int n_in,
                              void* d_out, int out_size, void* d_ws, size_t ws_size,
                              hipStream_t stream) {
    const float* xyz    = (const float*)d_in[0];   // [B,N,3]
    const float* center = (const float*)d_in[1];   // [B,M,3]
    const float* feats  = (const float*)d_in[2];   // [B,C,M]
    float* out = (float*)d_out;                    // [B,C,N]

    char*           ws     = (char*)d_ws;
    unsigned short* fm     = (unsigned short*)ws;
    int*            idx_ws = (int*)(ws + (size_t)B_ * M_ * C_ * 2);
    float*          w_ws   = (float*)(ws + (size_t)B_ * M_ * C_ * 2 + (size_t)B_ * N_ * 3 * 4);

    k_transpose<<<dim3(M_ / 64, C_ / 64, B_), dim3(64, 4), 0, stream>>>(feats, fm);
    k_threenn <<<dim3(N_ / PTS, B_), 256, 0, stream>>>(xyz, center, idx_ws, w_ws);
    k_interp  <<<NBN * NBC * B_, 256, 0, stream>>>(fm, idx_ws, w_ws, out);
}